// Round 1
// baseline (2039.994 us; speedup 1.0000x reference)
//
#include <hip/hip_runtime.h>
#include <hip/hip_bf16.h>

#define GLOBAL_AS __attribute__((address_space(1)))
#define LDS_AS    __attribute__((address_space(3)))

typedef __attribute__((ext_vector_type(8))) __bf16 bf16x8;
typedef __attribute__((ext_vector_type(4))) float  f32x4;

static constexpr int M = 8192;
static constexpr int N = 16384;
static constexpr int K = 4096;
static constexpr float W_EPS = 1e-6f;
#define INV_WCOUNT (1.0f / 67108864.0f)   // 1 / (16384*4096)

// ---------------------------------------------------------------- reduction
__global__ void absum_kernel(const float4* __restrict__ w, float* __restrict__ out) {
  const int total = (N * K) / 4;  // 16,777,216 float4
  int idx = blockIdx.x * blockDim.x + threadIdx.x;
  int stride = gridDim.x * blockDim.x;
  float s = 0.0f;
  for (int i = idx; i < total; i += stride) {
    float4 v = w[i];
    s += fabsf(v.x) + fabsf(v.y) + fabsf(v.z) + fabsf(v.w);
  }
  #pragma unroll
  for (int off = 32; off > 0; off >>= 1) s += __shfl_down(s, off, 64);
  __shared__ float red[4];
  const int lane = threadIdx.x & 63, wv = threadIdx.x >> 6;
  if (lane == 0) red[wv] = s;
  __syncthreads();
  if (threadIdx.x == 0) atomicAdd(out, red[0] + red[1] + red[2] + red[3]);
}

// ---------------------------------------------------------------- quantize W -> ternary bf16 {-1,0,+1}
__global__ void quant_kernel(const float4* __restrict__ w, ushort4* __restrict__ wq,
                             const float* __restrict__ wsum) {
  const float s   = fmaxf(wsum[0] * INV_WCOUNT, W_EPS);
  const float thr = 0.5f * s;
  const int total = (N * K) / 4;
  int idx = blockIdx.x * blockDim.x + threadIdx.x;
  int stride = gridDim.x * blockDim.x;
  for (int i = idx; i < total; i += stride) {
    float4 v = w[i];
    ushort4 q;
    q.x = v.x > thr ? 0x3F80u : (v.x < -thr ? 0xBF80u : 0u);
    q.y = v.y > thr ? 0x3F80u : (v.y < -thr ? 0xBF80u : 0u);
    q.z = v.z > thr ? 0x3F80u : (v.z < -thr ? 0xBF80u : 0u);
    q.w = v.w > thr ? 0x3F80u : (v.w < -thr ? 0xBF80u : 0u);
    wq[i] = q;
  }
}

// ---------------------------------------------------------------- cast x -> bf16 (RNE)
__device__ __forceinline__ unsigned short f2bf(float f) {
  unsigned int b = __float_as_uint(f);
  b += 0x7FFFu + ((b >> 16) & 1u);
  return (unsigned short)(b >> 16);
}

__global__ void castx_kernel(const float4* __restrict__ x, ushort4* __restrict__ xb) {
  const int total = (M * K) / 4;  // 8,388,608 float4
  int idx = blockIdx.x * blockDim.x + threadIdx.x;
  int stride = gridDim.x * blockDim.x;
  for (int i = idx; i < total; i += stride) {
    float4 v = x[i];
    ushort4 q;
    q.x = f2bf(v.x); q.y = f2bf(v.y); q.z = f2bf(v.z); q.w = f2bf(v.w);
    xb[i] = q;
  }
}

// ---------------------------------------------------------------- GEMM: out = (A @ B^T) * scale + bias
// A: M x K bf16 (x), B: N x K bf16 (ternary weights), out fp32.
// m97 structure: 128x128 tile, BK=32, 4 waves (2x2), 16x16x32 MFMA, 4x4 accs/wave.
__global__ __launch_bounds__(256) void gemm_kernel(
    const __hip_bfloat16* __restrict__ A,
    const __hip_bfloat16* __restrict__ B,
    const float* __restrict__ bias,
    const float* __restrict__ wsum,
    float* __restrict__ out) {
  __shared__ __hip_bfloat16 sA[128 * 32];  // 8 KB, row-major, NO padding (global_load_lds)
  __shared__ __hip_bfloat16 sB[128 * 32];  // 8 KB

  const int tid  = threadIdx.x;
  const int lane = tid & 63;
  const int wv   = tid >> 6;
  const int wm   = wv >> 1;      // wave row 0..1 (64 rows each)
  const int wn   = wv & 1;       // wave col 0..1 (64 cols each)
  const int tn   = blockIdx.x;   // N-tile
  const int tm   = blockIdx.y;   // M-tile

  // Staging: 512 chunks of 16B per tile; chunk c -> row c>>2, col8 (c&3)*8.
  // Thread tid handles c = tid and c = 256+tid. LDS dest must be wave-uniform
  // base + lane*16 -> unpadded row-major layout, base = (c - lane)*16 bytes.
  const int row_lo = tid >> 2;
  const int col0   = (tid & 3) * 8;
  const __hip_bfloat16* gA0 = A + (size_t)(tm * 128 + row_lo) * K + col0;
  const __hip_bfloat16* gA1 = gA0 + (size_t)64 * K;
  const __hip_bfloat16* gB0 = B + (size_t)(tn * 128 + row_lo) * K + col0;
  const __hip_bfloat16* gB1 = gB0 + (size_t)64 * K;
  const int cbase = tid & ~63;
  __hip_bfloat16* lA0 = sA + cbase * 8;
  __hip_bfloat16* lA1 = lA0 + 256 * 8;
  __hip_bfloat16* lB0 = sB + cbase * 8;
  __hip_bfloat16* lB1 = lB0 + 256 * 8;

  // Fragment bases: A-operand m = lane&15, k = (lane>>4)*8 + j
  const __hip_bfloat16* pa = sA + (wm * 64 + (lane & 15)) * 32 + (lane >> 4) * 8;
  const __hip_bfloat16* pb = sB + (wn * 64 + (lane & 15)) * 32 + (lane >> 4) * 8;

  const f32x4 zero = {0.f, 0.f, 0.f, 0.f};
  f32x4 acc[4][4];
  #pragma unroll
  for (int i = 0; i < 4; ++i)
    #pragma unroll
    for (int j = 0; j < 4; ++j) acc[i][j] = zero;

  for (int kt = 0; kt < K / 32; ++kt) {
    const int ko = kt * 32;
    __syncthreads();  // previous tile fully consumed
    __builtin_amdgcn_global_load_lds((const GLOBAL_AS void*)(gA0 + ko), (LDS_AS void*)lA0, 16, 0, 0);
    __builtin_amdgcn_global_load_lds((const GLOBAL_AS void*)(gA1 + ko), (LDS_AS void*)lA1, 16, 0, 0);
    __builtin_amdgcn_global_load_lds((const GLOBAL_AS void*)(gB0 + ko), (LDS_AS void*)lB0, 16, 0, 0);
    __builtin_amdgcn_global_load_lds((const GLOBAL_AS void*)(gB1 + ko), (LDS_AS void*)lB1, 16, 0, 0);
    __syncthreads();  // compiler emits s_waitcnt vmcnt(0) before s_barrier

    bf16x8 a[4], b[4];
    #pragma unroll
    for (int i = 0; i < 4; ++i) a[i] = *(const bf16x8*)(pa + i * 16 * 32);
    #pragma unroll
    for (int j = 0; j < 4; ++j) b[j] = *(const bf16x8*)(pb + j * 16 * 32);
    #pragma unroll
    for (int i = 0; i < 4; ++i)
      #pragma unroll
      for (int j = 0; j < 4; ++j)
        acc[i][j] = __builtin_amdgcn_mfma_f32_16x16x32_bf16(a[i], b[j], acc[i][j], 0, 0, 0);
  }

  // Epilogue: C/D layout col = lane&15 (n), row = (lane>>4)*4 + reg (m).
  const float s  = fmaxf(wsum[0] * INV_WCOUNT, W_EPS);
  const int   n0 = tn * 128 + wn * 64 + (lane & 15);
  const int   m0 = tm * 128 + wm * 64 + ((lane >> 4) << 2);
  float bj[4];
  #pragma unroll
  for (int j = 0; j < 4; ++j) bj[j] = bias[n0 + j * 16];
  #pragma unroll
  for (int i = 0; i < 4; ++i) {
    #pragma unroll
    for (int r = 0; r < 4; ++r) {
      float* orow = out + (size_t)(m0 + i * 16 + r) * N + n0;
      #pragma unroll
      for (int j = 0; j < 4; ++j)
        orow[j * 16] = acc[i][j][r] * s + bj[j];
    }
  }
}

// ---------------------------------------------------------------- launch
extern "C" void kernel_launch(void* const* d_in, const int* in_sizes, int n_in,
                              void* d_out, int out_size, void* d_ws, size_t ws_size,
                              hipStream_t stream) {
  const float* x    = (const float*)d_in[0];   // 8192 x 4096
  const float* w    = (const float*)d_in[1];   // 16384 x 4096
  const float* bias = (const float*)d_in[2];   // 16384
  float* out = (float*)d_out;                  // 8192 x 16384

  char* ws = (char*)d_ws;
  float* wsum = (float*)ws;                                        // 4 B
  __hip_bfloat16* Wq = (__hip_bfloat16*)(ws + 256);                // 134 MB
  __hip_bfloat16* Xb = (__hip_bfloat16*)(ws + 256 + (size_t)N * K * 2);  // 67 MB

  hipMemsetAsync(wsum, 0, sizeof(float), stream);
  absum_kernel<<<2048, 256, 0, stream>>>((const float4*)w, wsum);
  quant_kernel<<<8192, 256, 0, stream>>>((const float4*)w, (ushort4*)Wq, wsum);
  castx_kernel<<<4096, 256, 0, stream>>>((const float4*)x, (ushort4*)Xb);
  dim3 grid(N / 128, M / 128);
  gemm_kernel<<<grid, 256, 0, stream>>>(Xb, Wq, bias, wsum, out);
}